// Round 1
// baseline (92.114 us; speedup 1.0000x reference)
//
#include <hip/hip_runtime.h>
#include <math.h>

// Problem constants (from reference)
#define Hc 256      // ScaleSize H
#define Wc 256      // ScaleSize W
#define RHc 512     // resized H
#define RWc 256     // resized W
#define NPK 12      // picks per curve
#define KCUR 32     // curves per batch
#define SUBS 4      // sub-blocks per curve (parallelism for the write phase)
#define ROWS_PER_SUB (RHc / SUBS)   // 128 output rows per block

// out[m, r, w] = w0*soft[m,h0,w] + w1*soft[m,h1,w]
// soft[m,h,w]  = 0.01 + 0.9*(w == vIdx[m,h])
// (bilinear 256->512 half-pixel centers along H; W resize is identity)

__global__ __launch_bounds__(256) void cv_kernel(const float* __restrict__ vp,
                                                 const float* __restrict__ vmm,
                                                 float* __restrict__ out) {
    __shared__ float xs[NPK];
    __shared__ float fs[NPK];
    __shared__ int   s_nv;
    __shared__ int   idx[Hc];

    const int bid = blockIdx.x;
    const int m   = bid >> 2;          // curve 0..511
    const int sub = bid & (SUBS - 1);  // which quarter of output rows
    const int tid = threadIdx.x;
    const int b   = m / KCUR;          // batch index

    const float dtf = (float)(7000.0 / 255.0);   // (T1-T0)/(H-1), f32-cast of double

    // ---- Phase A: load picks, normalize, build sorted-prefix xp/fp ----
    if (tid == 0) {
        const float vmin = vmm[2 * b + 0];
        const float vmax = vmm[2 * b + 1];
        const float dv   = __fdiv_rn(__fsub_rn(vmax, vmin), 255.0f);
        int nv = 0;
        for (int i = 0; i < NPK; ++i) {
            const float t = vp[(size_t)m * NPK * 2 + i * 2 + 0];
            const float v = vp[(size_t)m * NPK * 2 + i * 2 + 1];
            const bool valid = (t > 0.0f);       // tn = t/dt > 0  <=>  t > 0
            xs[i] = valid ? __fdiv_rn(t, dtf) : INFINITY;
            fs[i] = __fdiv_rn(__fsub_rn(v, vmin), dv);
            nv += valid ? 1 : 0;
        }
        s_nv = nv;   // nv >= 4 per problem setup
    }
    __syncthreads();

    // ---- Phase B: per-h interpolation -> vIdx (np.interp semantics, f32-exact) ----
    {
        const int h   = tid;             // 0..255
        const float q = (float)h;
        const int nv  = s_nv;

        int ss = 0;
        #pragma unroll
        for (int i = 0; i < NPK; ++i) ss += (xs[i] <= q) ? 1 : 0;   // searchsorted right

        int himax = nv - 1; if (himax < 1) himax = 1;
        int hi = ss; if (hi < 1) hi = 1; if (hi > himax) hi = himax;
        const int lo = hi - 1;

        const float x0 = xs[lo], x1 = xs[hi];
        const float y0 = fs[lo], y1 = fs[hi];
        const float denom = __fsub_rn(x1, x0);
        const float safe  = (denom > 0.0f) ? denom : 1.0f;
        float val = __fadd_rn(y0,
                        __fmul_rn(__fdiv_rn(__fsub_rn(q, x0), safe),
                                  __fsub_rn(y1, y0)));
        int last = nv - 1; if (last < 0) last = 0;
        if (q <= xs[0])    val = fs[0];
        if (q >= xs[last]) val = fs[last];

        float rr = rintf(val);                 // jnp.round = half-to-even
        rr = fminf(fmaxf(rr, 0.0f), 255.0f);   // clip to [0, W-1]
        idx[h] = (int)rr;
    }
    __syncthreads();

    // ---- Phase C: stream the output rows (float4, fully coalesced) ----
    const int lane = tid & 63;
    const int rsub = tid >> 6;                     // 0..3: row within group of 4
    const int colb = lane * 4;
    float* outm = out + (size_t)m * RHc * RWc;

    #pragma unroll 4
    for (int it = 0; it < ROWS_PER_SUB / 4; ++it) {
        const int r = sub * ROWS_PER_SUB + it * 4 + rsub;

        int h0, h1; float w0, w1;
        if (r & 1) {                               // odd: c = (r-1)/2 + 0.25
            h0 = r >> 1; h1 = h0 + 1; if (h1 > Hc - 1) h1 = Hc - 1;
            w0 = 0.75f; w1 = 0.25f;
        } else {                                   // even: c = r/2 - 0.25
            h1 = r >> 1; h0 = h1 - 1; if (h0 < 0) h0 = 0;
            w0 = 0.25f; w1 = 0.75f;
        }
        const int c0 = idx[h0];
        const int c1 = idx[h1];
        const float a0 = 0.9f * w0;
        const float a1 = 0.9f * w1;

        float v0 = 0.01f, v1 = 0.01f, v2 = 0.01f, v3 = 0.01f;
        if (colb + 0 == c0) v0 += a0;  if (colb + 0 == c1) v0 += a1;
        if (colb + 1 == c0) v1 += a0;  if (colb + 1 == c1) v1 += a1;
        if (colb + 2 == c0) v2 += a0;  if (colb + 2 == c1) v2 += a1;
        if (colb + 3 == c0) v3 += a0;  if (colb + 3 == c1) v3 += a1;

        float4 val; val.x = v0; val.y = v1; val.z = v2; val.w = v3;
        *reinterpret_cast<float4*>(outm + (size_t)r * RWc + colb) = val;
    }
}

extern "C" void kernel_launch(void* const* d_in, const int* in_sizes, int n_in,
                              void* d_out, int out_size, void* d_ws, size_t ws_size,
                              hipStream_t stream) {
    const float* vp  = (const float*)d_in[0];   // VelPoints (16,32,12,2) f32
    const float* vmm = (const float*)d_in[1];   // VMM (16,2) f32
    float* out = (float*)d_out;                 // (16,32,512,256) f32

    const int nCurves = 16 * 32;                // 512
    cv_kernel<<<dim3(nCurves * SUBS), dim3(256), 0, stream>>>(vp, vmm, out);
}

// Round 3
// 56.535 us; speedup vs baseline: 1.6293x; 1.6293x over previous
//
#include <hip/hip_runtime.h>
#include <math.h>

// Problem constants (from reference)
#define Hc 256      // ScaleSize H
#define Wc 256      // ScaleSize W
#define RHc 512     // resized H
#define RWc 256     // resized W
#define NPK 12      // picks per curve
#define KCUR 32     // curves per batch
#define SUBS 4      // sub-blocks per curve (parallelism for the write phase)
#define ROWS_PER_SUB (RHc / SUBS)   // 128 output rows per block

typedef float f32x4 __attribute__((ext_vector_type(4)));

// out[m, r, w] = 0.01 + 0.9*(w0*(w==idx[h0]) + w1*(w==idx[h1]))
// (bilinear 256->512 half-pixel centers along H; W resize is identity;
//  even r: h1=r/2, h0=h1-1 clamp, w=(0.25,0.75); odd r: h0=r/2, h1=h0+1 clamp, w=(0.75,0.25))

__global__ __launch_bounds__(256) void cv_kernel(const float* __restrict__ vp,
                                                 const float* __restrict__ vmm,
                                                 float* __restrict__ out) {
    __shared__ float xs[NPK];
    __shared__ float fs[NPK];
    __shared__ int   s_nv;
    __shared__ int   idx[Hc];

    const int bid = blockIdx.x;
    const int m   = bid >> 2;          // curve 0..511
    const int sub = bid & (SUBS - 1);  // which quarter of output rows
    const int tid = threadIdx.x;
    const int b   = m / KCUR;          // batch index

    const float dtf = (float)(7000.0 / 255.0);   // (T1-T0)/(H-1), f32-cast of double

    // ---- Phase A: load picks, normalize, build sorted-prefix xp/fp ----
    if (tid == 0) {
        const float vmin = vmm[2 * b + 0];
        const float vmax = vmm[2 * b + 1];
        const float dv   = __fdiv_rn(__fsub_rn(vmax, vmin), 255.0f);
        int nv = 0;
        for (int i = 0; i < NPK; ++i) {
            const float t = vp[(size_t)m * NPK * 2 + i * 2 + 0];
            const float v = vp[(size_t)m * NPK * 2 + i * 2 + 1];
            const bool valid = (t > 0.0f);       // tn = t/dt > 0  <=>  t > 0
            xs[i] = valid ? __fdiv_rn(t, dtf) : INFINITY;
            fs[i] = __fdiv_rn(__fsub_rn(v, vmin), dv);
            nv += valid ? 1 : 0;
        }
        s_nv = nv;   // nv >= 4 per problem setup
    }
    __syncthreads();

    // ---- Phase B: per-h interpolation -> vIdx (np.interp semantics, f32-exact) ----
    {
        const int h   = tid;             // 0..255
        const float q = (float)h;
        const int nv  = s_nv;

        int ss = 0;
        #pragma unroll
        for (int i = 0; i < NPK; ++i) ss += (xs[i] <= q) ? 1 : 0;   // searchsorted right

        int himax = nv - 1; if (himax < 1) himax = 1;
        int hi = ss; if (hi < 1) hi = 1; if (hi > himax) hi = himax;
        const int lo = hi - 1;

        const float x0 = xs[lo], x1 = xs[hi];
        const float y0 = fs[lo], y1 = fs[hi];
        const float denom = __fsub_rn(x1, x0);
        const float safe  = (denom > 0.0f) ? denom : 1.0f;
        float val = __fadd_rn(y0,
                        __fmul_rn(__fdiv_rn(__fsub_rn(q, x0), safe),
                                  __fsub_rn(y1, y0)));
        int last = nv - 1; if (last < 0) last = 0;
        if (q <= xs[0])    val = fs[0];
        if (q >= xs[last]) val = fs[last];

        float rr = rintf(val);                 // jnp.round = half-to-even
        rr = fminf(fmaxf(rr, 0.0f), 255.0f);   // clip to [0, W-1]
        idx[h] = (int)rr;
    }
    __syncthreads();

    // ---- Phase C: stream output rows (float4 nontemporal, coalesced) ----
    // Per-block phase rotation: at any instant the 2048 lockstep blocks write
    // 4KiB chunks covering ALL residues mod 128KiB (avoids HBM channel camping).
    const int lane  = tid & 63;
    const int rsub  = tid >> 6;                    // 0..3: row within 4KiB chunk
    const int colb  = lane * 4;
    const int phase = bid & 31;
    float* outm = out + (size_t)m * RHc * RWc;

    #pragma unroll 4
    for (int it = 0; it < ROWS_PER_SUB / 4; ++it) {
        const int p = (it + phase) & 31;           // bijective chunk permutation
        const int r = sub * ROWS_PER_SUB + p * 4 + rsub;

        int h0, h1; float w0, w1;
        if (r & 1) {                               // odd: c = (r-1)/2 + 0.25
            h0 = r >> 1; h1 = h0 + 1; if (h1 > Hc - 1) h1 = Hc - 1;
            w0 = 0.75f; w1 = 0.25f;
        } else {                                   // even: c = r/2 - 0.25
            h1 = r >> 1; h0 = h1 - 1; if (h0 < 0) h0 = 0;
            w0 = 0.25f; w1 = 0.75f;
        }
        const int c0 = idx[h0];
        const int c1 = idx[h1];
        const float a0 = 0.9f * w0;
        const float a1 = 0.9f * w1;

        float v0 = 0.01f, v1 = 0.01f, v2 = 0.01f, v3 = 0.01f;
        if (colb + 0 == c0) v0 += a0;  if (colb + 0 == c1) v0 += a1;
        if (colb + 1 == c0) v1 += a0;  if (colb + 1 == c1) v1 += a1;
        if (colb + 2 == c0) v2 += a0;  if (colb + 2 == c1) v2 += a1;
        if (colb + 3 == c0) v3 += a0;  if (colb + 3 == c1) v3 += a1;

        f32x4 val; val.x = v0; val.y = v1; val.z = v2; val.w = v3;
        __builtin_nontemporal_store(val,
            reinterpret_cast<f32x4*>(outm + (size_t)r * RWc + colb));
    }
}

extern "C" void kernel_launch(void* const* d_in, const int* in_sizes, int n_in,
                              void* d_out, int out_size, void* d_ws, size_t ws_size,
                              hipStream_t stream) {
    const float* vp  = (const float*)d_in[0];   // VelPoints (16,32,12,2) f32
    const float* vmm = (const float*)d_in[1];   // VMM (16,2) f32
    float* out = (float*)d_out;                 // (16,32,512,256) f32

    const int nCurves = 16 * 32;                // 512
    cv_kernel<<<dim3(nCurves * SUBS), dim3(256), 0, stream>>>(vp, vmm, out);
}